// Round 1
// 111.345 us; speedup vs baseline: 1.0442x; 1.0442x over previous
//
#include <hip/hip_runtime.h>

// rfft512 over 32768 rows, one wave64 per row.
// z[n] = x[2n] + i*x[2n+1] -> FFT_256 (Stockham radix-4 DIF, 4 stages,
// float2 LDS ping-pong for the two true transposes, XOR-swizzled banks)
// -> rfft untangle via register shuffle -> bins 0..256.
//
// vs previous version:
//  * Initial LDS round-trip removed: lane t loads z[t], z[t+64], z[t+128],
//    z[t+192] directly (4x global_load_dwordx2, each 512B coalesced per wave).
//  * Stage D no longer writes LDS; the untangle partner Z[(256-k)&255] for
//    k=t+64j lives in lane (64-t)&63, register 3-j -> __shfl (lane 0
//    self-partners with register (4-j)&3).
//  * One sincos per lane feeds stages A/B/C: stage-B twiddle == stage-A
//    twiddle of lane t&60, stage-C == lane t&48 (cross-lane shuffle, exact).
//    Untangle: one sincos at k=t, then 3 rotations by exp(-i*pi/4).
//  => lgkmcnt(0) drains 5 -> 3, LDS instrs ~34 -> ~22/lane, sincos 7 -> 2.
//
// Wave-synchronous: each row is owned by exactly one wave, so stage
// boundaries need only "s_waitcnt lgkmcnt(0)" (wave64 lockstep), no
// __syncthreads. XOR swizzle phys(i)=i^((i>>2)&12) keeps all surviving
// stage read/write patterns bank-conflict-free.

#define NFFT 512
#define WPB  4   // waves (=rows) per 256-thread block

__device__ __forceinline__ int SW(int i) { return i ^ ((i >> 2) & 12); }

__device__ __forceinline__ void waveSyncLds() {
    asm volatile("s_waitcnt lgkmcnt(0)" ::: "memory");
}

__global__ __launch_bounds__(256) void rfft512_kernel(
    const float* __restrict__ x, float* __restrict__ out, int batch)
{
    __shared__ __align__(16) float2 lds[WPB][2][256];
    const int t = threadIdx.x & 63;
    const int w = threadIdx.x >> 6;
    long long b = (long long)blockIdx.x * WPB + w;
    if (b >= batch) b = batch - 1;   // safe clamp (grid divides exactly anyway)

    float2* buf0 = lds[w][0];
    float2* buf1 = lds[w][1];

    const float NEG2PI = -6.28318530717958647692f;

    // ---- Direct strided load: lane t owns z[t], z[t+64], z[t+128], z[t+192].
    // Each of the 4 loads covers 64 lanes x 8B = 512B contiguous.
    const float2* zin = (const float2*)(x + b * NFFT);
    float2 a  = zin[t];
    float2 bb = zin[t + 64];
    float2 c  = zin[t + 128];
    float2 d  = zin[t + 192];

    // Master twiddle: wA = exp(-2*pi*i * t / 256). Stages B/C derive theirs
    // by cross-lane shuffle (exact, no extra transcendentals).
    float sA, cA;
    __sincosf(NEG2PI * (float)t * (1.0f / 256.0f), &sA, &cA);

    // ---- Stage A: n=256, s=1 : p=t, wbase=4t, ws=1 (contiguous writes)
    {
        float apcr = a.x + c.x,  apci = a.y + c.y;
        float amcr = a.x - c.x,  amci = a.y - c.y;
        float bpdr = bb.x + d.x, bpdi = bb.y + d.y;
        float bmdr = bb.x - d.x, bmdi = bb.y - d.y;
        float y0r = apcr + bpdr, y0i = apci + bpdi;
        float u1r = amcr + bmdi, u1i = amci - bmdr;
        float u2r = apcr - bpdr, u2i = apci - bpdi;
        float u3r = amcr - bmdi, u3i = amci + bmdr;
        float w1r = cA, w1i = sA;
        float w2r = cA * cA - sA * sA, w2i = 2.0f * cA * sA;
        float w3r = w1r * w2r - w1i * w2i, w3i = w1r * w2i + w1i * w2r;
        int wb = (4 * t) ^ (t & 12);           // SW(4t), multiple of 4
        float4* d4 = (float4*)buf0;
        d4[wb >> 1]       = make_float4(y0r, y0i,
                                        w1r * u1r - w1i * u1i, w1r * u1i + w1i * u1r);
        d4[(wb >> 1) + 1] = make_float4(w2r * u2r - w2i * u2i, w2r * u2i + w2i * u2r,
                                        w3r * u3r - w3i * u3i, w3r * u3i + w3i * u3r);
    }
    waveSyncLds();

    // ---- Stage B: n=64, s=4 : p=t>>2, wbase=(t&3)+16*(t>>2), ws=4
    {
        int rb = SW(t);
        float2 a2 = buf0[rb], b2 = buf0[rb + 64], c2 = buf0[rb + 128], d2 = buf0[rb + 192];
        float apcr = a2.x + c2.x, apci = a2.y + c2.y;
        float amcr = a2.x - c2.x, amci = a2.y - c2.y;
        float bpdr = b2.x + d2.x, bpdi = b2.y + d2.y;
        float bmdr = b2.x - d2.x, bmdi = b2.y - d2.y;
        float y0r = apcr + bpdr, y0i = apci + bpdi;
        float u1r = amcr + bmdi, u1i = amci - bmdr;
        float u2r = apcr - bpdr, u2i = apci - bpdi;
        float u3r = amcr - bmdi, u3i = amci + bmdr;
        // wB(t) = exp(-2*pi*i*(t>>2)/64) = wA evaluated at lane (t & 60)
        float cB = __shfl(cA, t & 60);
        float sB = __shfl(sA, t & 60);
        float w1r = cB, w1i = sB;
        float w2r = cB * cB - sB * sB, w2i = 2.0f * cB * sB;
        float w3r = w1r * w2r - w1i * w2i, w3i = w1r * w2i + w1i * w2r;
        int wbase = (t & 3) + 16 * (t >> 2);
        buf1[SW(wbase)]      = make_float2(y0r, y0i);
        buf1[SW(wbase + 4)]  = make_float2(w1r * u1r - w1i * u1i, w1r * u1i + w1i * u1r);
        buf1[SW(wbase + 8)]  = make_float2(w2r * u2r - w2i * u2i, w2r * u2i + w2i * u2r);
        buf1[SW(wbase + 12)] = make_float2(w3r * u3r - w3i * u3i, w3r * u3i + w3i * u3r);
    }
    waveSyncLds();

    // ---- Stage C: n=16, s=16 : p=t>>4, wbase=(t&15)+64*(t>>4), ws=16
    {
        int rb = SW(t);
        float2 a2 = buf1[rb], b2 = buf1[rb + 64], c2 = buf1[rb + 128], d2 = buf1[rb + 192];
        float apcr = a2.x + c2.x, apci = a2.y + c2.y;
        float amcr = a2.x - c2.x, amci = a2.y - c2.y;
        float bpdr = b2.x + d2.x, bpdi = b2.y + d2.y;
        float bmdr = b2.x - d2.x, bmdi = b2.y - d2.y;
        float y0r = apcr + bpdr, y0i = apci + bpdi;
        float u1r = amcr + bmdi, u1i = amci - bmdr;
        float u2r = apcr - bpdr, u2i = apci - bpdi;
        float u3r = amcr - bmdi, u3i = amci + bmdr;
        // wC(t) = exp(-2*pi*i*(t>>4)/16) = wA evaluated at lane (t & 48)
        float cC = __shfl(cA, t & 48);
        float sC = __shfl(sA, t & 48);
        float w1r = cC, w1i = sC;
        float w2r = cC * cC - sC * sC, w2i = 2.0f * cC * sC;
        float w3r = w1r * w2r - w1i * w2i, w3i = w1r * w2i + w1i * w2r;
        int wbase = (t & 15) + 64 * (t >> 4);
        buf0[SW(wbase)]      = make_float2(y0r, y0i);
        buf0[SW(wbase + 16)] = make_float2(w1r * u1r - w1i * u1i, w1r * u1i + w1i * u1r);
        buf0[SW(wbase + 32)] = make_float2(w2r * u2r - w2i * u2i, w2r * u2i + w2i * u2r);
        buf0[SW(wbase + 48)] = make_float2(w3r * u3r - w3i * u3i, w3r * u3i + w3i * u3r);
    }
    waveSyncLds();

    // ---- Stage D: n=4, s=64 : p=0 (unit twiddles), lane-local.
    // zr[j],zi[j] = Z[t + 64j] stay in registers; no LDS write needed.
    float zr[4], zi[4];
    {
        int rb = SW(t);
        float2 a2 = buf0[rb], b2 = buf0[rb + 64], c2 = buf0[rb + 128], d2 = buf0[rb + 192];
        float apcr = a2.x + c2.x, apci = a2.y + c2.y;
        float amcr = a2.x - c2.x, amci = a2.y - c2.y;
        float bpdr = b2.x + d2.x, bpdi = b2.y + d2.y;
        float bmdr = b2.x - d2.x, bmdi = b2.y - d2.y;
        zr[0] = apcr + bpdr; zi[0] = apci + bpdi;
        zr[1] = amcr + bmdi; zi[1] = amci - bmdr;
        zr[2] = apcr - bpdr; zi[2] = apci - bpdi;
        zr[3] = amcr - bmdi; zi[3] = amci + bmdr;
    }

    // ---- rfft untangle: X[k] = A + exp(-2*pi*i*k/512)*B, k = t+64j.
    // Partner Z[(256-k)&255] = lane (64-t)&63, register 3-j (lane 0: self,
    // register (4-j)&3). Twiddle: sincos once at k=t, then rotate by
    // exp(-i*pi/4) per j (exact constant, 4 FMA-class ops).
    float* outRe = out + b * 257;
    float* outIm = out + (long long)batch * 257 + b * 257;
    const int lp = (64 - t) & 63;
    float sU, cU;
    __sincosf(NEG2PI * (float)t * (1.0f / 512.0f), &sU, &cU);
    const float RC = 0.70710678118654752440f;  // cos(pi/4)
#pragma unroll
    for (int j = 0; j < 4; ++j) {
        float pr = __shfl(zr[3 - j], lp);
        float pi = __shfl(zi[3 - j], lp);
        if (t == 0) { pr = zr[(4 - j) & 3]; pi = zi[(4 - j) & 3]; }
        int k = t + 64 * j;
        float Ar = 0.5f * (zr[j] + pr);
        float Ai = 0.5f * (zi[j] - pi);
        float Br = 0.5f * (zi[j] + pi);
        float Bi = -0.5f * (zr[j] - pr);
        outRe[k] = Ar + cU * Br - sU * Bi;
        outIm[k] = Ai + cU * Bi + sU * Br;
        float nc = RC * (cU + sU);             // (cU + i sU) * (RC - i RC)
        float ns = RC * (sU - cU);
        cU = nc; sU = ns;
    }
    if (t == 0) {
        outRe[256] = zr[0] - zi[0];   // X[256] = Re(Z[0]) - Im(Z[0])
        outIm[256] = 0.0f;
    }
}

extern "C" void kernel_launch(void* const* d_in, const int* in_sizes, int n_in,
                              void* d_out, int out_size, void* d_ws, size_t ws_size,
                              hipStream_t stream)
{
    const float* x = (const float*)d_in[0];
    float* out = (float*)d_out;
    const int batch = in_sizes[0] / NFFT;        // 32768
    const int grid = (batch + WPB - 1) / WPB;    // 8192 blocks of 256
    rfft512_kernel<<<grid, 256, 0, stream>>>(x, out, batch);
}